// Round 8
// baseline (197.606 us; speedup 1.0000x reference)
//
#include <hip/hip_runtime.h>
#include <cstdint>
#include <cstddef>

// Problem constants
#define NCLUS 64
#define DIM   128
#define BATCH 512              // K of the Gram reduction (bytes per fp8 row)
#define QCOLS 8192             // NCLUS*DIM
#define NPAIR 2016             // 64*63/2
#define TSTRB (QCOLS * BATCH)  // BYTES per tensor in fp8 (4,194,304)
#define FP8SCALE 256.0f        // q^2 * 256 -> e4m3 (max 256 < 448, no clip)

typedef float f32x4 __attribute__((ext_vector_type(4)));
typedef long  lx2  __attribute__((ext_vector_type(2)));

// q2t layout: row (t, c*128+d) of 512 bytes over b. Within each 64-byte
// k-chunk, 8-byte units are PERMUTED: global unit u stored at p=(u&3)*2+(u>>2),
// so the 16-B chunk at slot q = [kstep0 | kstep1] for MFMA-quarter q ->
// one 16-B global load feeds both ksteps of a lane. (Same layout as R5-R7.)

// ---------------------------------------------------------------------------
// Kernel 1: softmax over D=128 -> q^2*256 -> fp8 e4m3 -> permuted-transposed
// q2t. Coalesced: one 32-lane group per softmax row (R7, verified).
// ---------------------------------------------------------------------------
__global__ __launch_bounds__(256) void softmax_q2_kernel(
    const float* __restrict__ emb, uint8_t* __restrict__ q2t,
    float* __restrict__ dotPart) {
  __shared__ uint32_t T32[2 * 64 * 33];      // 16.5 KB; [t*64+b][col] stride 33
  __shared__ float red[4];
  const int c  = blockIdx.y;
  const int bq = blockIdx.x;
  const int tid = threadIdx.x;
  const int w = tid >> 6, lane = tid & 63;
  const int sub = lane >> 5;                 // which of the 2 rows this iter
  const int col = lane & 31;                 // float4 index within the row

  float4 qa = {0.f, 0.f, 0.f, 0.f};
  float dot = 0.f;

#pragma unroll
  for (int k = 0; k < 16; ++k) {
    const int t  = k & 1;
    const int bl = w * 16 + (k >> 1) * 2 + sub;   // 0..63
    const int b  = bq * 64 + bl;
    const float4 v = *(const float4*)(emb +
        ((size_t)(t * BATCH + b) * QCOLS + (size_t)c * DIM + col * 4));

    float mx = fmaxf(fmaxf(v.x, v.y), fmaxf(v.z, v.w));
#pragma unroll
    for (int off = 1; off < 32; off <<= 1) mx = fmaxf(mx, __shfl_xor(mx, off));
    float e0 = __expf(v.x - mx), e1 = __expf(v.y - mx);
    float e2 = __expf(v.z - mx), e3 = __expf(v.w - mx);
    float s = (e0 + e1) + (e2 + e3);
#pragma unroll
    for (int off = 1; off < 32; off <<= 1) s += __shfl_xor(s, off);
    const float inv = 1.0f / s;
    const float q0 = e0 * inv, q1 = e1 * inv, q2 = e2 * inv, q3 = e3 * inv;

    if (t == 0) { qa.x = q0; qa.y = q1; qa.z = q2; qa.w = q3; }
    else        { dot += qa.x * q0 + qa.y * q1 + qa.z * q2 + qa.w * q3; }

    int pk = __builtin_amdgcn_cvt_pk_fp8_f32(q0 * q0 * FP8SCALE,
                                             q1 * q1 * FP8SCALE, 0, false);
    pk = __builtin_amdgcn_cvt_pk_fp8_f32(q2 * q2 * FP8SCALE,
                                         q3 * q3 * FP8SCALE, pk, true);
    T32[(t * 64 + bl) * 33 + col] = (uint32_t)pk;
  }
  __syncthreads();

  // write-out: 1024 chunks of 16 B in permuted unit order
#pragma unroll
  for (int it = 0; it < 4; ++it) {
    int ch = it * 256 + tid;               // 0..1023
    int t = ch >> 9, d = (ch >> 2) & 127, b16 = ch & 3;
    const int dq = d >> 2, sh = (d & 3) * 8;
    uint32_t w0 = 0, w1 = 0, w2 = 0, w3 = 0;
#pragma unroll
    for (int r = 0; r < 4; ++r) {
      w0 |= ((T32[(t * 64 + b16 * 8 + r) * 33 + dq] >> sh) & 0xFFu) << (8 * r);
      w1 |= ((T32[(t * 64 + b16 * 8 + 4 + r) * 33 + dq] >> sh) & 0xFFu) << (8 * r);
      w2 |= ((T32[(t * 64 + 32 + b16 * 8 + r) * 33 + dq] >> sh) & 0xFFu) << (8 * r);
      w3 |= ((T32[(t * 64 + 32 + b16 * 8 + 4 + r) * 33 + dq] >> sh) & 0xFFu) << (8 * r);
    }
    size_t off = (size_t)t * TSTRB + (size_t)(c * DIM + d) * BATCH +
                 (size_t)bq * 64 + b16 * 16;
    uint4 o; o.x = w0; o.y = w1; o.z = w2; o.w = w3;
    *(uint4*)(q2t + off) = o;
  }

#pragma unroll
  for (int off = 1; off < 64; off <<= 1) dot += __shfl_xor(dot, off);
  if (lane == 0) red[w] = dot;
  __syncthreads();
  if (tid == 0) dotPart[blockIdx.y * 8 + blockIdx.x] = red[0] + red[1] + red[2] + red[3];
}

// ---------------------------------------------------------------------------
// Kernel 2: fp8 Gram tile (J,I), J<I, both tensors (16 K-slots of 64 bytes).
// NO LDS in the K-loop: each lane loads its MFMA fragments DIRECTLY from
// global (L1/L2-resident panels; permuted layout = 16 contiguous bytes per
// frag). Register double-buffer, no barriers, fully unrolled. 4 waves (2x2),
// each 4x4 of 16x16x32 fp8 MFMA. XCD supertile ordering for L2 locality.
// ---------------------------------------------------------------------------
__global__ __launch_bounds__(256, 3) void gram_sqrt_kernel(
    const uint8_t* __restrict__ q2t, float* __restrict__ Spart) {
  __shared__ float red[4];

  // ---- pair decode: XCD partition + 8x8 supertile order ----
  int sidx = ((int)blockIdx.x & 7) * 252 + ((int)blockIdx.x >> 3);
  int q = sidx, gi = 0;
  while (q >= 64 * gi + 28) { q -= 64 * gi + 28; ++gi; }
  int I, J;
  if (q < 64 * gi) {
    int gj = q >> 6, r = q & 63;
    I = gi * 8 + (r >> 3);
    J = gj * 8 + (r & 7);
  } else {
    int dq = q - 64 * gi;
    int il = 1;
    while (il * (il + 1) / 2 <= dq) ++il;
    I = gi * 8 + il;
    J = gi * 8 + (dq - il * (il - 1) / 2);
  }

  const int tid  = threadIdx.x;
  const int lane = tid & 63, w = tid >> 6;
  const int wm = w & 1, wn = w >> 1;
  const int l15 = lane & 15, qtr = lane >> 4;

  // per-lane fragment base addresses (tensor 0, slot 0)
  // frag row = panel*128 + (wm|wn)*64 + i*16 + l15 ; 16-B chunk = qtr
  const uint8_t* Ab[4];
  const uint8_t* Bb[4];
#pragma unroll
  for (int i = 0; i < 4; ++i) {
    Ab[i] = q2t + (size_t)(J * DIM + wm * 64 + i * 16 + l15) * BATCH + qtr * 16;
    Bb[i] = q2t + (size_t)(I * DIM + wn * 64 + i * 16 + l15) * BATCH + qtr * 16;
  }

  f32x4 acc[4][4];
#pragma unroll
  for (int i = 0; i < 4; ++i)
#pragma unroll
    for (int j = 0; j < 4; ++j) acc[i][j] = (f32x4){0.f, 0.f, 0.f, 0.f};

  float S0 = 0.f, S1 = 0.f;

  lx2 Ac[4], Bc[4];
#pragma unroll
  for (int i = 0; i < 4; ++i) {          // preload slot 0
    Ac[i] = *(const lx2*)(Ab[i]);
    Bc[i] = *(const lx2*)(Bb[i]);
  }

#pragma unroll
  for (int tm = 0; tm < 16; ++tm) {      // slot = (tensor tm>>3, k-chunk tm&7)
    lx2 An[4], Bn[4];
    if (tm < 15) {                       // prefetch next slot into registers
      const size_t noff = (size_t)((tm + 1) >> 3) * TSTRB +
                          (size_t)((tm + 1) & 7) * 64;
#pragma unroll
      for (int i = 0; i < 4; ++i) {
        An[i] = *(const lx2*)(Ab[i] + noff);
        Bn[i] = *(const lx2*)(Bb[i] + noff);
      }
    }

#pragma unroll
    for (int i = 0; i < 4; ++i)
#pragma unroll
      for (int j = 0; j < 4; ++j)
        acc[i][j] = __builtin_amdgcn_mfma_f32_16x16x32_fp8_fp8(
            Ac[i].x, Bc[j].x, acc[i][j], 0, 0, 0);
#pragma unroll
    for (int i = 0; i < 4; ++i)
#pragma unroll
      for (int j = 0; j < 4; ++j)
        acc[i][j] = __builtin_amdgcn_mfma_f32_16x16x32_fp8_fp8(
            Ac[i].y, Bc[j].y, acc[i][j], 0, 0, 0);

    if (tm == 7) {                       // harvest tensor 0, reset acc
#pragma unroll
      for (int i = 0; i < 4; ++i)
#pragma unroll
        for (int j = 0; j < 4; ++j) {
#pragma unroll
          for (int e = 0; e < 4; ++e) S0 += sqrtf(acc[i][j][e]);
          acc[i][j] = (f32x4){0.f, 0.f, 0.f, 0.f};
        }
    }

    if (tm < 15) {                       // roll the register buffers
#pragma unroll
      for (int i = 0; i < 4; ++i) { Ac[i] = An[i]; Bc[i] = Bn[i]; }
    }
  }

  // harvest tensor 1
#pragma unroll
  for (int i = 0; i < 4; ++i)
#pragma unroll
    for (int j = 0; j < 4; ++j)
#pragma unroll
      for (int e = 0; e < 4; ++e) S1 += sqrtf(acc[i][j][e]);

  // G was scaled by 256*256 -> sqrt scaled by 256
  float local = (S0 + S1) * (1.0f / 256.0f);
#pragma unroll
  for (int off = 1; off < 64; off <<= 1) local += __shfl_xor(local, off);
  if (lane == 0) red[w] = local;
  __syncthreads();
  if (tid == 0) Spart[blockIdx.x] = red[0] + red[1] + red[2] + red[3];
}

// ---------------------------------------------------------------------------
// Kernel 3: reduce partials and combine.
// P[0..511] = dot partials, P[512..2527] = S partials.
// loss = -dot/(B*N_C) - S/((N_C^2-N_C)*sqrt(B))
// ---------------------------------------------------------------------------
__global__ __launch_bounds__(256) void finalize_kernel(
    const float* __restrict__ P, float* __restrict__ out) {
  __shared__ float rd[8];
  const int tid = threadIdx.x;
  float d = 0.f, s = 0.f;
  for (int i = tid; i < 512; i += 256) d += P[i];
  for (int i = tid; i < NPAIR; i += 256) s += P[512 + i];
#pragma unroll
  for (int off = 1; off < 64; off <<= 1) { d += __shfl_xor(d, off); s += __shfl_xor(s, off); }
  const int w = tid >> 6;
  if ((tid & 63) == 0) { rd[w] = d; rd[4 + w] = s; }
  __syncthreads();
  if (tid == 0) {
    float dt = rd[0] + rd[1] + rd[2] + rd[3];
    float st = rd[4] + rd[5] + rd[6] + rd[7];
    out[0] = -dt / 32768.0f - st / (4032.0f * 22.62741699796952f);
  }
}

extern "C" void kernel_launch(void* const* d_in, const int* in_sizes, int n_in,
                              void* d_out, int out_size, void* d_ws, size_t ws_size,
                              hipStream_t stream) {
  const float* emb = (const float*)d_in[0];
  float* out = (float*)d_out;
  float* P = (float*)d_ws;                                 // 2528 partials
  uint8_t* q2t = (uint8_t*)d_ws + 16384;                   // 2 x 8192 x 512 fp8

  softmax_q2_kernel<<<dim3(8, 64), 256, 0, stream>>>(emb, q2t, P);
  gram_sqrt_kernel<<<dim3(NPAIR), 256, 0, stream>>>(q2t, P + 512);
  finalize_kernel<<<1, 256, 0, stream>>>(P, out);
}

// Round 9
// 139.340 us; speedup vs baseline: 1.4182x; 1.4182x over previous
//
#include <hip/hip_runtime.h>
#include <cstdint>
#include <cstddef>

// Problem constants
#define NCLUS 64
#define DIM   128
#define BATCH 512              // K of the Gram reduction (bytes per fp8 row)
#define QCOLS 8192             // NCLUS*DIM
#define NPAIR 2016             // 64*63/2
#define TSTRB (QCOLS * BATCH)  // BYTES per tensor in fp8 (4,194,304)
#define FP8SCALE 256.0f        // q^2 * 256 -> e4m3 (max 256 < 448, no clip)

typedef float f32x4  __attribute__((ext_vector_type(4)));
typedef float f32x16 __attribute__((ext_vector_type(16)));
typedef long  lx2    __attribute__((ext_vector_type(2)));

// q2t layout (unchanged since R5): row (t, c*128+d) of 512 bytes over b.
// Within each 64-byte k-chunk, 8-byte units are PERMUTED: unit u at
// p=(u&3)*2+(u>>2), i.e. 16-B slot q holds units [q | 4+q]. For the 32x32x16
// fp8 MFMA (lane h=lane>>5, row r=lane&31, 8 B per kstep of 16), slot h holds
// ksteps {0,2} and slot h+2 holds ksteps {1,3} -> two ds_read_b128 per
// row-group cover all 4 ksteps of a 64-B chunk.

__device__ __forceinline__ void ld_lds16(const void* g, void* l) {
  __builtin_amdgcn_global_load_lds(
      (__attribute__((address_space(1))) void*)g,
      (__attribute__((address_space(3))) void*)l, 16, 0, 0);
}

#define SYNC_VM4()  asm volatile("s_waitcnt vmcnt(4)\n\ts_barrier" ::: "memory")
#define SYNC_VM0()  asm volatile("s_waitcnt vmcnt(0)\n\ts_barrier" ::: "memory")
#define SYNC_LGKM() asm volatile("s_waitcnt lgkmcnt(0)\n\ts_barrier" ::: "memory")

// ---------------------------------------------------------------------------
// Kernel 1: softmax over D=128 -> q^2*256 -> fp8 e4m3 -> permuted-transposed
// q2t. Coalesced: one 32-lane group per softmax row (R7, verified).
// ---------------------------------------------------------------------------
__global__ __launch_bounds__(256) void softmax_q2_kernel(
    const float* __restrict__ emb, uint8_t* __restrict__ q2t,
    float* __restrict__ dotPart) {
  __shared__ uint32_t T32[2 * 64 * 33];      // 16.5 KB; [t*64+b][col] stride 33
  __shared__ float red[4];
  const int c  = blockIdx.y;
  const int bq = blockIdx.x;
  const int tid = threadIdx.x;
  const int w = tid >> 6, lane = tid & 63;
  const int sub = lane >> 5;                 // which of the 2 rows this iter
  const int col = lane & 31;                 // float4 index within the row

  float4 qa = {0.f, 0.f, 0.f, 0.f};
  float dot = 0.f;

#pragma unroll
  for (int k = 0; k < 16; ++k) {
    const int t  = k & 1;
    const int bl = w * 16 + (k >> 1) * 2 + sub;   // 0..63
    const int b  = bq * 64 + bl;
    const float4 v = *(const float4*)(emb +
        ((size_t)(t * BATCH + b) * QCOLS + (size_t)c * DIM + col * 4));

    float mx = fmaxf(fmaxf(v.x, v.y), fmaxf(v.z, v.w));
#pragma unroll
    for (int off = 1; off < 32; off <<= 1) mx = fmaxf(mx, __shfl_xor(mx, off));
    float e0 = __expf(v.x - mx), e1 = __expf(v.y - mx);
    float e2 = __expf(v.z - mx), e3 = __expf(v.w - mx);
    float s = (e0 + e1) + (e2 + e3);
#pragma unroll
    for (int off = 1; off < 32; off <<= 1) s += __shfl_xor(s, off);
    const float inv = 1.0f / s;
    const float q0 = e0 * inv, q1 = e1 * inv, q2 = e2 * inv, q3 = e3 * inv;

    if (t == 0) { qa.x = q0; qa.y = q1; qa.z = q2; qa.w = q3; }
    else        { dot += qa.x * q0 + qa.y * q1 + qa.z * q2 + qa.w * q3; }

    int pk = __builtin_amdgcn_cvt_pk_fp8_f32(q0 * q0 * FP8SCALE,
                                             q1 * q1 * FP8SCALE, 0, false);
    pk = __builtin_amdgcn_cvt_pk_fp8_f32(q2 * q2 * FP8SCALE,
                                         q3 * q3 * FP8SCALE, pk, true);
    T32[(t * 64 + bl) * 33 + col] = (uint32_t)pk;
  }
  __syncthreads();

  // write-out: 1024 chunks of 16 B in permuted unit order
#pragma unroll
  for (int it = 0; it < 4; ++it) {
    int ch = it * 256 + tid;               // 0..1023
    int t = ch >> 9, d = (ch >> 2) & 127, b16 = ch & 3;
    const int dq = d >> 2, sh = (d & 3) * 8;
    uint32_t w0 = 0, w1 = 0, w2 = 0, w3 = 0;
#pragma unroll
    for (int r = 0; r < 4; ++r) {
      w0 |= ((T32[(t * 64 + b16 * 8 + r) * 33 + dq] >> sh) & 0xFFu) << (8 * r);
      w1 |= ((T32[(t * 64 + b16 * 8 + 4 + r) * 33 + dq] >> sh) & 0xFFu) << (8 * r);
      w2 |= ((T32[(t * 64 + 32 + b16 * 8 + r) * 33 + dq] >> sh) & 0xFFu) << (8 * r);
      w3 |= ((T32[(t * 64 + 32 + b16 * 8 + 4 + r) * 33 + dq] >> sh) & 0xFFu) << (8 * r);
    }
    size_t off = (size_t)t * TSTRB + (size_t)(c * DIM + d) * BATCH +
                 (size_t)bq * 64 + b16 * 16;
    uint4 o; o.x = w0; o.y = w1; o.z = w2; o.w = w3;
    *(uint4*)(q2t + off) = o;
  }

#pragma unroll
  for (int off = 1; off < 64; off <<= 1) dot += __shfl_xor(dot, off);
  if (lane == 0) red[w] = dot;
  __syncthreads();
  if (tid == 0) dotPart[blockIdx.y * 8 + blockIdx.x] = red[0] + red[1] + red[2] + red[3];
}

// ---------------------------------------------------------------------------
// Kernel 2: fp8 Gram tile (J,I), J<I, both tensors per block (16 chunks of 64
// K-bytes), 128x128 tile, 4 waves (2x2), 32x32x16 fp8 MFMA (2x2 per wave,
// 4060 FLOP/cyc vs 3378 for 16x16). Double-buffered LDS (2x16 KB, 4 bl/CU),
// one-chunk-ahead prefetch (vmcnt(4)), same staging+rotation as R7 (0-conflict
// verified); reader = 2 ds_read_b128 per row-group covering all 4 ksteps.
// ---------------------------------------------------------------------------
__global__ __launch_bounds__(256, 4) void gram_sqrt_kernel(
    const uint8_t* __restrict__ q2t, float* __restrict__ Spart) {
  __shared__ uint8_t L[32768 + 16];  // buf0 A@0 B@8192, buf1 A@16384 B@24576

  // ---- pair decode: XCD partition + 8x8 supertile order ----
  int sidx = ((int)blockIdx.x & 7) * 252 + ((int)blockIdx.x >> 3);
  int q = sidx, gi = 0;
  while (q >= 64 * gi + 28) { q -= 64 * gi + 28; ++gi; }
  int I, J;
  if (q < 64 * gi) {
    int gj = q >> 6, r = q & 63;
    I = gi * 8 + (r >> 3);
    J = gj * 8 + (r & 7);
  } else {
    int dq = q - 64 * gi;
    int il = 1;
    while (il * (il + 1) / 2 <= dq) ++il;
    I = gi * 8 + il;
    J = gi * 8 + (dq - il * (il - 1) / 2);
  }

  const uint8_t* baseA = q2t + (size_t)J * (DIM * BATCH);  // 64 KB panels
  const uint8_t* baseB = q2t + (size_t)I * (DIM * BATCH);

  const int tid  = threadIdx.x;
  const int lane = tid & 63, w = tid >> 6;
  const int wm = w & 1, wn = w >> 1;

  // staging (unchanged): slot t holds (row r=t>>2, phys p=t&3) <- global
  // chunk (p-(r>>1))&3, i.e. chunk c sits at phys (c+(r>>1))&3.
  const int t0 = tid, t1 = 256 + tid;
  const int r0s = t0 >> 2, r1s = t1 >> 2;
  const int c0s = ((t0 & 3) - ((r0s >> 1) & 3)) & 3;
  const int c1s = ((t1 & 3) - ((r1s >> 1) & 3)) & 3;
  const size_t g0 = (size_t)r0s * BATCH + c0s * 16;
  const size_t g1 = (size_t)r1s * BATCH + c1s * 16;
  uint8_t* Lb = L;
  const int ldsw = w * 1024;   // wave-uniform dest base within a 4 KB round

  // 32x32 reader: lane h = lane>>5 (k-half), r31 = lane&31 (row in group).
  // row R = wm*64 + g*32 + r31; phys chunk for ksteps{0,2} = (h+(r31>>1))&3,
  // for ksteps{1,3} = (h+2+(r31>>1))&3  (wm*32, g*16 vanish mod 4).
  const int h = lane >> 5, r31 = lane & 31;
  const int sg0 = ((h     + (r31 >> 1)) & 3) * 16;
  const int sg1 = ((h + 2 + (r31 >> 1)) & 3) * 16;
  const int ArowO = (wm * 64 + r31) * 64;           // + g*2048
  const int BrowO = 8192 + (wn * 64 + r31) * 64;    // + g*2048

  f32x16 acc[2][2];
#pragma unroll
  for (int i = 0; i < 2; ++i)
#pragma unroll
    for (int j = 0; j < 2; ++j) acc[i][j] = (f32x16)(0.f);

  float S0 = 0.f, S1 = 0.f;

  // prologue: stage chunk 0 into buf0
  ld_lds16(baseA + g0, Lb + ldsw);
  ld_lds16(baseA + g1, Lb + 4096 + ldsw);
  ld_lds16(baseB + g0, Lb + 8192 + ldsw);
  ld_lds16(baseB + g1, Lb + 12288 + ldsw);

  for (int m = 0; m < 16; ++m) {
    if (m < 15) {                       // prefetch chunk m+1 into buf (m+1)&1
      const int mi = m + 1;
      const int bb = (mi & 1) << 14;
      const size_t ck = (size_t)(mi >> 3) * TSTRB + (size_t)(mi & 7) * 64;
      ld_lds16(baseA + ck + g0, Lb + bb + ldsw);
      ld_lds16(baseA + ck + g1, Lb + bb + 4096 + ldsw);
      ld_lds16(baseB + ck + g0, Lb + bb + 8192 + ldsw);
      ld_lds16(baseB + ck + g1, Lb + bb + 12288 + ldsw);
      SYNC_VM4();                       // oldest 4 (= chunk m) have landed
    } else {
      SYNC_VM0();
    }

    const int be = (m & 1) << 14;
    lx2 a02[2], a13[2], b02[2], b13[2];
#pragma unroll
    for (int g = 0; g < 2; ++g) {
      a02[g] = *(const lx2*)(Lb + be + ArowO + g * 2048 + sg0);  // ksteps 0,2
      a13[g] = *(const lx2*)(Lb + be + ArowO + g * 2048 + sg1);  // ksteps 1,3
      b02[g] = *(const lx2*)(Lb + be + BrowO + g * 2048 + sg0);
      b13[g] = *(const lx2*)(Lb + be + BrowO + g * 2048 + sg1);
    }
#pragma unroll
    for (int i = 0; i < 2; ++i)
#pragma unroll
      for (int j = 0; j < 2; ++j) {
        acc[i][j] = __builtin_amdgcn_mfma_f32_32x32x16_fp8_fp8(
            a02[i].x, b02[j].x, acc[i][j], 0, 0, 0);
        acc[i][j] = __builtin_amdgcn_mfma_f32_32x32x16_fp8_fp8(
            a13[i].x, b13[j].x, acc[i][j], 0, 0, 0);
        acc[i][j] = __builtin_amdgcn_mfma_f32_32x32x16_fp8_fp8(
            a02[i].y, b02[j].y, acc[i][j], 0, 0, 0);
        acc[i][j] = __builtin_amdgcn_mfma_f32_32x32x16_fp8_fp8(
            a13[i].y, b13[j].y, acc[i][j], 0, 0, 0);
      }

    if (m == 7) {                       // harvest tensor 0, reset acc
#pragma unroll
      for (int i = 0; i < 2; ++i)
#pragma unroll
        for (int j = 0; j < 2; ++j) {
#pragma unroll
          for (int e = 0; e < 16; ++e) S0 += sqrtf(acc[i][j][e]);
          acc[i][j] = (f32x16)(0.f);
        }
    }

    SYNC_LGKM();                        // buf(m&1) reads done before overwrite
  }

  // harvest tensor 1
#pragma unroll
  for (int i = 0; i < 2; ++i)
#pragma unroll
    for (int j = 0; j < 2; ++j)
#pragma unroll
      for (int e = 0; e < 16; ++e) S1 += sqrtf(acc[i][j][e]);

  // G was scaled by 256*256 -> sqrt scaled by 256
  float local = (S0 + S1) * (1.0f / 256.0f);
#pragma unroll
  for (int off = 1; off < 64; off <<= 1) local += __shfl_xor(local, off);
  float* fred = (float*)(L + 32768);
  if (lane == 0) fred[w] = local;
  __syncthreads();
  if (tid == 0) Spart[blockIdx.x] = fred[0] + fred[1] + fred[2] + fred[3];
}

// ---------------------------------------------------------------------------
// Kernel 3: reduce partials and combine.
// P[0..511] = dot partials, P[512..2527] = S partials.
// loss = -dot/(B*N_C) - S/((N_C^2-N_C)*sqrt(B))
// ---------------------------------------------------------------------------
__global__ __launch_bounds__(256) void finalize_kernel(
    const float* __restrict__ P, float* __restrict__ out) {
  __shared__ float rd[8];
  const int tid = threadIdx.x;
  float d = 0.f, s = 0.f;
  for (int i = tid; i < 512; i += 256) d += P[i];
  for (int i = tid; i < NPAIR; i += 256) s += P[512 + i];
#pragma unroll
  for (int off = 1; off < 64; off <<= 1) { d += __shfl_xor(d, off); s += __shfl_xor(s, off); }
  const int w = tid >> 6;
  if ((tid & 63) == 0) { rd[w] = d; rd[4 + w] = s; }
  __syncthreads();
  if (tid == 0) {
    float dt = rd[0] + rd[1] + rd[2] + rd[3];
    float st = rd[4] + rd[5] + rd[6] + rd[7];
    out[0] = -dt / 32768.0f - st / (4032.0f * 22.62741699796952f);
  }
}

extern "C" void kernel_launch(void* const* d_in, const int* in_sizes, int n_in,
                              void* d_out, int out_size, void* d_ws, size_t ws_size,
                              hipStream_t stream) {
  const float* emb = (const float*)d_in[0];
  float* out = (float*)d_out;
  float* P = (float*)d_ws;                                 // 2528 partials
  uint8_t* q2t = (uint8_t*)d_ws + 16384;                   // 2 x 8192 x 512 fp8

  softmax_q2_kernel<<<dim3(8, 64), 256, 0, stream>>>(emb, q2t, P);
  gram_sqrt_kernel<<<dim3(NPAIR), 256, 0, stream>>>(q2t, P + 512);
  finalize_kernel<<<1, 256, 0, stream>>>(P, out);
}

// Round 10
// 126.980 us; speedup vs baseline: 1.5562x; 1.0973x over previous
//
#include <hip/hip_runtime.h>
#include <cstdint>
#include <cstddef>

// Problem constants
#define NCLUS 64
#define DIM   128
#define BATCH 512              // K of the Gram reduction (bytes per fp8 row)
#define QCOLS 8192             // NCLUS*DIM
#define NPAIR 2016             // 64*63/2
#define TSTRB (QCOLS * BATCH)  // BYTES per tensor in fp8 (4,194,304)
#define FP8SCALE 256.0f        // q^2 * 256 -> e4m3 (max 256 < 448, no clip)

typedef float f32x16 __attribute__((ext_vector_type(16)));
typedef int   i32x4  __attribute__((ext_vector_type(4)));
typedef int   i32x8  __attribute__((ext_vector_type(8)));

// q2t layout (R10): row (t, c*128+d) of 512 bytes over b, PLAIN byte order
// (byte b at offset b). The 32x32x64 MX MFMA lane (h=lane>>5, r=lane&31)
// needs k-bytes [h*32, h*32+32) = 16-B chunks {2h, 2h+1} of each 64-B
// k-chunk -> two ds_read_b128 per row-group. LDS rows store the 4 chunks
// rotated by rot(r)=(r+(r>>2))&3 (bank-checked: exactly 2-way per 16-lane
// phase = free).

__device__ __forceinline__ void ld_lds16(const void* g, void* l) {
  __builtin_amdgcn_global_load_lds(
      (__attribute__((address_space(1))) void*)g,
      (__attribute__((address_space(3))) void*)l, 16, 0, 0);
}

#define SYNC_VM4()  asm volatile("s_waitcnt vmcnt(4)\n\ts_barrier" ::: "memory")
#define SYNC_VM0()  asm volatile("s_waitcnt vmcnt(0)\n\ts_barrier" ::: "memory")
#define SYNC_LGKM() asm volatile("s_waitcnt lgkmcnt(0)\n\ts_barrier" ::: "memory")

// ---------------------------------------------------------------------------
// Kernel 1: softmax over D=128 -> q^2*256 -> fp8 e4m3 -> transposed q2t
// (plain byte order). Coalesced reads: one 32-lane group per softmax row.
// ---------------------------------------------------------------------------
__global__ __launch_bounds__(256) void softmax_q2_kernel(
    const float* __restrict__ emb, uint8_t* __restrict__ q2t,
    float* __restrict__ dotPart) {
  __shared__ uint32_t T32[2 * 64 * 33];      // 16.5 KB; [t*64+b][col] stride 33
  __shared__ float red[4];
  const int c  = blockIdx.y;
  const int bq = blockIdx.x;
  const int tid = threadIdx.x;
  const int w = tid >> 6, lane = tid & 63;
  const int sub = lane >> 5;                 // which of the 2 rows this iter
  const int col = lane & 31;                 // float4 index within the row

  float4 qa = {0.f, 0.f, 0.f, 0.f};
  float dot = 0.f;

#pragma unroll
  for (int k = 0; k < 16; ++k) {
    const int t  = k & 1;
    const int bl = w * 16 + (k >> 1) * 2 + sub;   // 0..63
    const int b  = bq * 64 + bl;
    const float4 v = *(const float4*)(emb +
        ((size_t)(t * BATCH + b) * QCOLS + (size_t)c * DIM + col * 4));

    float mx = fmaxf(fmaxf(v.x, v.y), fmaxf(v.z, v.w));
#pragma unroll
    for (int off = 1; off < 32; off <<= 1) mx = fmaxf(mx, __shfl_xor(mx, off));
    float e0 = __expf(v.x - mx), e1 = __expf(v.y - mx);
    float e2 = __expf(v.z - mx), e3 = __expf(v.w - mx);
    float s = (e0 + e1) + (e2 + e3);
#pragma unroll
    for (int off = 1; off < 32; off <<= 1) s += __shfl_xor(s, off);
    const float inv = 1.0f / s;
    const float q0 = e0 * inv, q1 = e1 * inv, q2 = e2 * inv, q3 = e3 * inv;

    if (t == 0) { qa.x = q0; qa.y = q1; qa.z = q2; qa.w = q3; }
    else        { dot += qa.x * q0 + qa.y * q1 + qa.z * q2 + qa.w * q3; }

    int pk = __builtin_amdgcn_cvt_pk_fp8_f32(q0 * q0 * FP8SCALE,
                                             q1 * q1 * FP8SCALE, 0, false);
    pk = __builtin_amdgcn_cvt_pk_fp8_f32(q2 * q2 * FP8SCALE,
                                         q3 * q3 * FP8SCALE, pk, true);
    T32[(t * 64 + bl) * 33 + col] = (uint32_t)pk;
  }
  __syncthreads();

  // write-out: 1024 chunks of 16 B, PLAIN order: chunk b16 = b [b16*16,+16)
#pragma unroll
  for (int it = 0; it < 4; ++it) {
    int ch = it * 256 + tid;               // 0..1023
    int t = ch >> 9, d = (ch >> 2) & 127, b16 = ch & 3;
    const int dq = d >> 2, sh = (d & 3) * 8;
    uint32_t w0 = 0, w1 = 0, w2 = 0, w3 = 0;
#pragma unroll
    for (int r = 0; r < 4; ++r) {
      w0 |= ((T32[(t * 64 + b16 * 16 +  0 + r) * 33 + dq] >> sh) & 0xFFu) << (8 * r);
      w1 |= ((T32[(t * 64 + b16 * 16 +  4 + r) * 33 + dq] >> sh) & 0xFFu) << (8 * r);
      w2 |= ((T32[(t * 64 + b16 * 16 +  8 + r) * 33 + dq] >> sh) & 0xFFu) << (8 * r);
      w3 |= ((T32[(t * 64 + b16 * 16 + 12 + r) * 33 + dq] >> sh) & 0xFFu) << (8 * r);
    }
    size_t off = (size_t)t * TSTRB + (size_t)(c * DIM + d) * BATCH +
                 (size_t)bq * 64 + b16 * 16;
    uint4 o; o.x = w0; o.y = w1; o.z = w2; o.w = w3;
    *(uint4*)(q2t + off) = o;
  }

#pragma unroll
  for (int off = 1; off < 64; off <<= 1) dot += __shfl_xor(dot, off);
  if (lane == 0) red[w] = dot;
  __syncthreads();
  if (tid == 0) dotPart[blockIdx.y * 8 + blockIdx.x] = red[0] + red[1] + red[2] + red[3];
}

// ---------------------------------------------------------------------------
// Kernel 2: MX-scaled fp8 Gram tile (J,I), J<I, both tensors per block
// (16 chunks of 64 K-bytes). 128x128 tile, 4 waves (2x2), each wave 2x2 of
// 32x32x64 f8f6f4 MFMA with unit scales (2x plain-fp8 rate; ONE MFMA eats a
// full 64-B k-chunk). Double-buffered LDS (2x16 KB), vmcnt(4) prefetch.
// rot(r)=(r+(r>>2))&3 chunk rotation: 2-way (free) banks on read AND write.
// ---------------------------------------------------------------------------
__global__ __launch_bounds__(256, 4) void gram_sqrt_kernel(
    const uint8_t* __restrict__ q2t, float* __restrict__ Spart) {
  __shared__ uint8_t L[32768 + 16];  // buf0 A@0 B@8192, buf1 A@16384 B@24576

  // ---- pair decode: XCD partition + 8x8 supertile order ----
  int sidx = ((int)blockIdx.x & 7) * 252 + ((int)blockIdx.x >> 3);
  int q = sidx, gi = 0;
  while (q >= 64 * gi + 28) { q -= 64 * gi + 28; ++gi; }
  int I, J;
  if (q < 64 * gi) {
    int gj = q >> 6, r = q & 63;
    I = gi * 8 + (r >> 3);
    J = gj * 8 + (r & 7);
  } else {
    int dq = q - 64 * gi;
    int il = 1;
    while (il * (il + 1) / 2 <= dq) ++il;
    I = gi * 8 + il;
    J = gi * 8 + (dq - il * (il - 1) / 2);
  }

  const uint8_t* baseA = q2t + (size_t)J * (DIM * BATCH);  // 64 KB panels
  const uint8_t* baseB = q2t + (size_t)I * (DIM * BATCH);

  const int tid  = threadIdx.x;
  const int lane = tid & 63, w = tid >> 6;
  const int wm = w & 1, wn = w >> 1;

  // staging: slot tid covers (row r, phys p) <- global chunk c=(p-rot(r))&3
  const int t0 = tid, t1 = 256 + tid;
  const int r0s = t0 >> 2, r1s = t1 >> 2;
  const int rot0 = (r0s + (r0s >> 2)) & 3;
  const int rot1 = (r1s + (r1s >> 2)) & 3;
  const int c0s = ((t0 & 3) - rot0) & 3;
  const int c1s = ((t1 & 3) - rot1) & 3;
  const size_t g0 = (size_t)r0s * BATCH + c0s * 16;
  const size_t g1 = (size_t)r1s * BATCH + c1s * 16;
  uint8_t* Lb = L;
  const int ldsw = w * 1024;   // wave-uniform dest base within a 4 KB round

  // reader: row R = wm*64 + g*32 + r31; rot(R) == (r31+(r31>>2))&3.
  // lane h needs global chunks {2h, 2h+1} at phys ((q+rot)&3)*16.
  const int h = lane >> 5, r31 = lane & 31;
  const int rot = (r31 + (r31 >> 2)) & 3;
  const int ro1 = ((2 * h + rot) & 3) * 16;       // chunk 2h   (k h*32..+16)
  const int ro2 = ((2 * h + 1 + rot) & 3) * 16;   // chunk 2h+1 (k h*32+16..+16)
  const int ArowO = (wm * 64 + r31) * 64;         // + g*2048
  const int BrowO = 8192 + (wn * 64 + r31) * 64;  // + g*2048

  f32x16 acc[2][2];
#pragma unroll
  for (int i = 0; i < 2; ++i)
#pragma unroll
    for (int j = 0; j < 2; ++j) acc[i][j] = (f32x16)(0.f);

  float S0 = 0.f, S1 = 0.f;

  // prologue: stage chunk 0 into buf0
  ld_lds16(baseA + g0, Lb + ldsw);
  ld_lds16(baseA + g1, Lb + 4096 + ldsw);
  ld_lds16(baseB + g0, Lb + 8192 + ldsw);
  ld_lds16(baseB + g1, Lb + 12288 + ldsw);

  for (int m = 0; m < 16; ++m) {
    if (m < 15) {                       // prefetch chunk m+1 into buf (m+1)&1
      const int mi = m + 1;
      const int bb = (mi & 1) << 14;
      const size_t ck = (size_t)(mi >> 3) * TSTRB + (size_t)(mi & 7) * 64;
      ld_lds16(baseA + ck + g0, Lb + bb + ldsw);
      ld_lds16(baseA + ck + g1, Lb + bb + 4096 + ldsw);
      ld_lds16(baseB + ck + g0, Lb + bb + 8192 + ldsw);
      ld_lds16(baseB + ck + g1, Lb + bb + 12288 + ldsw);
      SYNC_VM4();                       // oldest 4 (= chunk m) have landed
    } else {
      SYNC_VM0();
    }

    const int be = (m & 1) << 14;
    i32x4 alo[2], ahi[2], blo[2], bhi[2];
#pragma unroll
    for (int g = 0; g < 2; ++g) {
      alo[g] = *(const i32x4*)(Lb + be + ArowO + g * 2048 + ro1);
      ahi[g] = *(const i32x4*)(Lb + be + ArowO + g * 2048 + ro2);
      blo[g] = *(const i32x4*)(Lb + be + BrowO + g * 2048 + ro1);
      bhi[g] = *(const i32x4*)(Lb + be + BrowO + g * 2048 + ro2);
    }
    i32x8 af[2], bf[2];
#pragma unroll
    for (int g = 0; g < 2; ++g) {
      af[g] = (i32x8){alo[g].x, alo[g].y, alo[g].z, alo[g].w,
                      ahi[g].x, ahi[g].y, ahi[g].z, ahi[g].w};
      bf[g] = (i32x8){blo[g].x, blo[g].y, blo[g].z, blo[g].w,
                      bhi[g].x, bhi[g].y, bhi[g].z, bhi[g].w};
    }
    // ONE scaled MFMA per acc per 64-B chunk; fmt 0 = fp8 e4m3, scale 2^0
#pragma unroll
    for (int i = 0; i < 2; ++i)
#pragma unroll
      for (int j = 0; j < 2; ++j)
        acc[i][j] = __builtin_amdgcn_mfma_scale_f32_32x32x64_f8f6f4(
            af[i], bf[j], acc[i][j], 0, 0, 0, 0x7F7F7F7F, 0, 0x7F7F7F7F);

    if (m == 7) {                       // harvest tensor 0, reset acc
#pragma unroll
      for (int i = 0; i < 2; ++i)
#pragma unroll
        for (int j = 0; j < 2; ++j) {
#pragma unroll
          for (int e = 0; e < 16; ++e) S0 += sqrtf(acc[i][j][e]);
          acc[i][j] = (f32x16)(0.f);
        }
    }

    SYNC_LGKM();                        // buf(m&1) reads done before overwrite
  }

  // harvest tensor 1
#pragma unroll
  for (int i = 0; i < 2; ++i)
#pragma unroll
    for (int j = 0; j < 2; ++j)
#pragma unroll
      for (int e = 0; e < 16; ++e) S1 += sqrtf(acc[i][j][e]);

  // G was scaled by 256*256 -> sqrt scaled by 256
  float local = (S0 + S1) * (1.0f / 256.0f);
#pragma unroll
  for (int off = 1; off < 64; off <<= 1) local += __shfl_xor(local, off);
  float* fred = (float*)(L + 32768);
  if (lane == 0) fred[w] = local;
  __syncthreads();
  if (tid == 0) Spart[blockIdx.x] = fred[0] + fred[1] + fred[2] + fred[3];
}

// ---------------------------------------------------------------------------
// Kernel 3: reduce partials and combine.
// P[0..511] = dot partials, P[512..2527] = S partials.
// loss = -dot/(B*N_C) - S/((N_C^2-N_C)*sqrt(B))
// ---------------------------------------------------------------------------
__global__ __launch_bounds__(256) void finalize_kernel(
    const float* __restrict__ P, float* __restrict__ out) {
  __shared__ float rd[8];
  const int tid = threadIdx.x;
  float d = 0.f, s = 0.f;
  for (int i = tid; i < 512; i += 256) d += P[i];
  for (int i = tid; i < NPAIR; i += 256) s += P[512 + i];
#pragma unroll
  for (int off = 1; off < 64; off <<= 1) { d += __shfl_xor(d, off); s += __shfl_xor(s, off); }
  const int w = tid >> 6;
  if ((tid & 63) == 0) { rd[w] = d; rd[4 + w] = s; }
  __syncthreads();
  if (tid == 0) {
    float dt = rd[0] + rd[1] + rd[2] + rd[3];
    float st = rd[4] + rd[5] + rd[6] + rd[7];
    out[0] = -dt / 32768.0f - st / (4032.0f * 22.62741699796952f);
  }
}

extern "C" void kernel_launch(void* const* d_in, const int* in_sizes, int n_in,
                              void* d_out, int out_size, void* d_ws, size_t ws_size,
                              hipStream_t stream) {
  const float* emb = (const float*)d_in[0];
  float* out = (float*)d_out;
  float* P = (float*)d_ws;                                 // 2528 partials
  uint8_t* q2t = (uint8_t*)d_ws + 16384;                   // 2 x 8192 x 512 fp8

  softmax_q2_kernel<<<dim3(8, 64), 256, 0, stream>>>(emb, q2t, P);
  gram_sqrt_kernel<<<dim3(NPAIR), 256, 0, stream>>>(q2t, P + 512);
  finalize_kernel<<<1, 256, 0, stream>>>(P, out);
}